// Round 15
// baseline (1271.321 us; speedup 1.0000x reference)
//
#include <hip/hip_runtime.h>

#define TOKENS   32768
#define DIM      256
#define KCB      1024
#define CBOOKS   8
#define NTOK     2048
#define ZQ_ELEMS (TOKENS * DIM)
#define EPS_GAP  2.0e-2f

typedef _Float16 f16x8 __attribute__((ext_vector_type(8)));
typedef float    f32x4 __attribute__((ext_vector_type(4)));

// ---------------------------------------------------------------------------
// numpy pairwise sum of squares (verified bit-exact, r6).
// ---------------------------------------------------------------------------
__device__ float np_pairwise_sumsq_256(const float4* a4) {
  #pragma clang fp contract(off)
  float h[2];
  for (int hh = 0; hh < 2; ++hh) {
    const float4* b = a4 + hh * 32;
    float4 v0 = b[0], v1 = b[1];
    float r0 = v0.x * v0.x, r1 = v0.y * v0.y, r2 = v0.z * v0.z, r3 = v0.w * v0.w;
    float r4 = v1.x * v1.x, r5 = v1.y * v1.y, r6 = v1.z * v1.z, r7 = v1.w * v1.w;
    for (int t = 1; t < 16; ++t) {
      float4 w0 = b[2 * t], w1 = b[2 * t + 1];
      r0 = r0 + w0.x * w0.x; r1 = r1 + w0.y * w0.y;
      r2 = r2 + w0.z * w0.z; r3 = r3 + w0.w * w0.w;
      r4 = r4 + w1.x * w1.x; r5 = r5 + w1.y * w1.y;
      r6 = r6 + w1.z * w1.z; r7 = r7 + w1.w * w1.w;
    }
    h[hh] = ((r0 + r1) + (r2 + r3)) + ((r4 + r5) + (r6 + r7));
  }
  return h[0] + h[1];
}

__device__ __forceinline__ float4 f4_muladd(float4 a, float4 b, float4 c) {
  #pragma clang fp contract(off)
  float4 r;
  r.x = a.x * b.x + c.x;
  r.y = a.y * b.y + c.y;
  r.z = a.z * b.z + c.z;
  r.w = a.w * b.w + c.w;
  return r;
}

__global__ __launch_bounds__(256) void rvq_norms_kernel(
    const float* __restrict__ cb, float* __restrict__ sume) {
  int row = blockIdx.x * 256 + threadIdx.x;
  sume[row] = np_pairwise_sumsq_256((const float4*)&cb[(size_t)row * DIM]);
}

// ---------------------------------------------------------------------------
// MFMA screen (r11-verified values/orientation/merge). T14 async-stage:
// LOADG (global->reg, issued BEFORE compute) is split from CVW (convert +
// LDS write, AFTER compute) so the vmcnt wait hides under the MFMAs.
// ---------------------------------------------------------------------------
__global__ __launch_bounds__(256) void rvq_screen_kernel(
    const float* __restrict__ xr, const float* __restrict__ cbc,
    const float* __restrict__ sume, float4* __restrict__ part,
    int* __restrict__ fix_cnt) {
  __shared__ f16x8 ldsA[2][2][8][64];   // 32 KB
  __shared__ f16x8 ldsB[2][2][8][64];   // 32 KB

  const int tid  = threadIdx.x;
  const int lane = tid & 63;
  const int wid  = tid >> 6;
  const int wm   = wid & 1;
  const int wn   = wid >> 1;
  const int mtile = blockIdx.x & 255;
  const int ntile = blockIdx.x >> 8;
  const int m0  = mtile * 128;
  const int nk0 = ntile * 128;

  if (blockIdx.x == 0 && tid == 0) *fix_cnt = 0;

  f32x4 acc[4][4];
  #pragma unroll
  for (int mi = 0; mi < 4; ++mi)
    #pragma unroll
    for (int ni = 0; ni < 4; ++ni) acc[mi][ni] = (f32x4){0.f, 0.f, 0.f, 0.f};

  float4 ga[2][2], gb[2][2];            // in-flight staging registers

#define LOADG(KC_)                                                           \
  { _Pragma("unroll")                                                        \
    for (int j = 0; j < 2; ++j) {                                            \
      int item = j * 256 + tid;                                              \
      int row = item >> 2, q8 = item & 3;                                    \
      const float* sa = &xr[(size_t)(m0 + row) * DIM + (KC_) * 32 + q8 * 8]; \
      ga[j][0] = *(const float4*)sa; ga[j][1] = *(const float4*)(sa + 4);    \
      const float* sb = &cbc[(size_t)(nk0 + row) * DIM + (KC_) * 32 + q8*8]; \
      gb[j][0] = *(const float4*)sb; gb[j][1] = *(const float4*)(sb + 4);    \
    } }

#define CVW(BUF)                                                             \
  { _Pragma("unroll")                                                        \
    for (int j = 0; j < 2; ++j) {                                            \
      int item = j * 256 + tid;                                              \
      int row = item >> 2, q8 = item & 3;                                    \
      int fl = (row & 15) + 16 * q8, fr = row >> 4;                          \
      float4 u = ga[j][0], v = ga[j][1];                                     \
      float xv[8] = {u.x, u.y, u.z, u.w, v.x, v.y, v.z, v.w};                \
      f16x8 hi, lo;                                                          \
      _Pragma("unroll")                                                      \
      for (int i = 0; i < 8; ++i) {                                          \
        _Float16 h = (_Float16)xv[i];                                        \
        hi[i] = h; lo[i] = (_Float16)(xv[i] - (float)h);                     \
      }                                                                      \
      ldsA[BUF][0][fr][fl] = hi; ldsA[BUF][1][fr][fl] = lo;                  \
      float4 ub = gb[j][0], vb = gb[j][1];                                   \
      float ev[8] = {ub.x, ub.y, ub.z, ub.w, vb.x, vb.y, vb.z, vb.w};        \
      f16x8 hib, lob;                                                        \
      _Pragma("unroll")                                                      \
      for (int i = 0; i < 8; ++i) {                                          \
        _Float16 h = (_Float16)ev[i];                                        \
        hib[i] = h; lob[i] = (_Float16)(ev[i] - (float)h);                   \
      }                                                                      \
      ldsB[BUF][0][fr][fl] = hib; ldsB[BUF][1][fr][fl] = lob;                \
    } }

#define COMPUTE(BUF)                                                         \
  { f16x8 ah[4], al[4], bh[4], bl[4];                                        \
    _Pragma("unroll")                                                        \
    for (int i = 0; i < 4; ++i) {                                            \
      ah[i] = ldsA[BUF][0][wm * 4 + i][lane];                                \
      al[i] = ldsA[BUF][1][wm * 4 + i][lane];                                \
      bh[i] = ldsB[BUF][0][wn * 4 + i][lane];                                \
      bl[i] = ldsB[BUF][1][wn * 4 + i][lane];                                \
    }                                                                        \
    _Pragma("unroll")                                                        \
    for (int mi = 0; mi < 4; ++mi)                                           \
      _Pragma("unroll")                                                      \
      for (int ni = 0; ni < 4; ++ni) {                                       \
        acc[mi][ni] = __builtin_amdgcn_mfma_f32_16x16x32_f16(                \
            ah[mi], bh[ni], acc[mi][ni], 0, 0, 0);                           \
        acc[mi][ni] = __builtin_amdgcn_mfma_f32_16x16x32_f16(                \
            al[mi], bh[ni], acc[mi][ni], 0, 0, 0);                           \
        acc[mi][ni] = __builtin_amdgcn_mfma_f32_16x16x32_f16(                \
            ah[mi], bl[ni], acc[mi][ni], 0, 0, 0);                           \
      } }

  LOADG(0)
  CVW(0)
  __syncthreads();
  for (int kc = 0; kc < 8; ++kc) {
    if (kc < 7) LOADG(kc + 1)           // issue loads early (in flight)
    COMPUTE(kc & 1)                     // MFMAs on current buffer
    if (kc < 7) CVW((kc + 1) & 1)       // vmcnt wait lands here, after MFMAs
    __syncthreads();
  }
#undef LOADG
#undef CVW
#undef COMPUTE

  // ---- epilogue: per-wave (64-k half) best/second, then cross-wn merge ----
  float* scr = (float*)&ldsA[0][0][0][0];
  const int n0 = ntile * 128 + wn * 64;
  float se[4];
  #pragma unroll
  for (int ni = 0; ni < 4; ++ni) se[ni] = sume[n0 + ni * 16 + (lane & 15)];

  #pragma unroll
  for (int mi = 0; mi < 4; ++mi) {
    #pragma unroll
    for (int r = 0; r < 4; ++r) {
      float v1 = 3.0e38f, v2 = 3.0e38f; int i1 = 0x7fffffff;
      #pragma unroll
      for (int ni = 0; ni < 4; ++ni) {
        float key = fmaf(-2.0f, acc[mi][ni][r], se[ni]);
        int   k   = n0 + ni * 16 + (lane & 15);
        if (key < v1 || (key == v1 && k < i1)) { v2 = v1; v1 = key; i1 = k; }
        else { v2 = fminf(v2, key); }
      }
      #pragma unroll
      for (int off = 1; off < 16; off <<= 1) {
        float ov1 = __shfl_xor(v1, off, 64);
        int   oi1 = __shfl_xor(i1, off, 64);
        float ov2 = __shfl_xor(v2, off, 64);
        if (ov1 < v1 || (ov1 == v1 && oi1 < i1)) { v2 = fminf(ov2, v1); v1 = ov1; i1 = oi1; }
        else { v2 = fminf(v2, fminf(ov1, ov2)); }
      }
      if ((lane & 15) == 0) {
        int tl = wm * 64 + mi * 16 + (lane >> 4) * 4 + r;   // 0..127
        scr[wn * 384 + tl]       = v1;
        scr[wn * 384 + 128 + tl] = __int_as_float(i1);
        scr[wn * 384 + 256 + tl] = v2;
      }
    }
  }
  __syncthreads();

  if (tid < 128) {
    float av1 = scr[tid],        av2 = scr[256 + tid];
    int   ai  = __float_as_int(scr[128 + tid]);
    float bv1 = scr[384 + tid],  bv2 = scr[384 + 256 + tid];
    int   bi  = __float_as_int(scr[384 + 128 + tid]);
    float v1, v2; int i1;
    if (bv1 < av1) { v1 = bv1; i1 = bi; v2 = fminf(bv2, av1); }   // tie -> a (lower k)
    else           { v1 = av1; i1 = ai; v2 = fminf(av2, bv1); }
    part[(size_t)ntile * TOKENS + m0 + tid] =
        make_float4(v1, __int_as_float(i1), v2, 0.0f);
  }
}

// Merge 8 n-tile partials; near-ties appended to compact fixup list.
__global__ __launch_bounds__(256) void rvq_merge_kernel(
    const float4* __restrict__ part, int* __restrict__ idx_ws,
    int* __restrict__ fix_list, int* __restrict__ fix_cnt,
    float* __restrict__ idxf) {
  int token = blockIdx.x * 256 + threadIdx.x;
  float v1 = 3.0e38f, v2 = 3.0e38f; int i1 = 0x7fffffff;
  #pragma unroll
  for (int j = 0; j < 8; ++j) {
    float4 p = part[(size_t)j * TOKENS + token];
    float ov1 = p.x, ov2 = p.z; int oi1 = __float_as_int(p.y);
    if (ov1 < v1 || (ov1 == v1 && oi1 < i1)) { v2 = fminf(ov2, v1); v1 = ov1; i1 = oi1; }
    else { v2 = fminf(v2, fminf(ov1, ov2)); }
  }
  idx_ws[token] = i1;
  if (v2 - v1 < EPS_GAP) {
    int pos = atomicAdd(fix_cnt, 1);
    fix_list[pos] = token;
  }
  int b = token >> 11, n = token & (NTOK - 1);
  idxf[(size_t)b * (CBOOKS * NTOK) + n] = (float)i1;
}

// Exact numpy rescan over the compacted flagged-token list (r14-verified:
// register-budgeted, unroll-1, no spill).
__global__ __launch_bounds__(256, 2) void rvq_fixup_kernel(
    const float* __restrict__ xr, const float* __restrict__ cbc,
    const float* __restrict__ sume, const int* __restrict__ fix_list,
    const int* __restrict__ fix_cnt, int* __restrict__ idx_ws,
    float* __restrict__ idxf) {
  #pragma clang fp contract(off)
  __shared__ float xs[DIM];
  __shared__ float redv[4];
  __shared__ int   redi[4];
  __shared__ float sxv_sh;
  const int tid  = threadIdx.x;
  const int nfix = *fix_cnt;

  #pragma unroll 1
  for (int i = blockIdx.x; i < nfix; i += gridDim.x) {
    int token = fix_list[i];
    __syncthreads();                           // xs reuse guard
    if (tid < 64)
      ((float4*)xs)[tid] = ((const float4*)xr)[(size_t)token * 64 + tid];
    __syncthreads();
    // inline np-exact sumx: lanes 0-15 run the 16 stride-8 chains, then
    // a 4-step butterfly reproduces the exact pairwise combine tree.
    if (tid < 64) {
      float s = 0.f;
      if ((tid & 63) < 16) {
        int j = tid & 7, hh = (tid >> 3) & 1;
        const float* bb = xs + hh * 128;
        float r = bb[j] * bb[j];
        #pragma unroll 1
        for (int t = 1; t < 16; ++t) r = r + bb[8 * t + j] * bb[8 * t + j];
        s = r;
      }
      #pragma unroll
      for (int off = 1; off <= 8; off <<= 1)
        s = s + __shfl_xor(s, off, 64);        // commutative pairs -> exact tree
      if (tid == 0) sxv_sh = s;
    }
    __syncthreads();
    float sxv = sxv_sh;
    float bv = 3.0e38f; int bi = 0x7fffffff;
    #pragma unroll 1
    for (int kk = 0; kk < 4; ++kk) {
      int k = kk * 256 + tid;
      float4 vacc = {0.f, 0.f, 0.f, 0.f};
      #pragma unroll 1
      for (int t = 0; t < 16; ++t) {
        float4 ab = vacc;
        #pragma unroll
        for (int j = 3; j >= 0; --j) {         // reverse-chained npyv block
          float4 xq = *(const float4*)&xs[t * 16 + j * 4];
          float4 eq = *(const float4*)&cbc[(size_t)k * DIM + t * 16 + j * 4];
          ab = f4_muladd(xq, eq, ab);
        }
        vacc = ab;
      }
      float dot = (vacc.x + vacc.y) + (vacc.z + vacc.w);
      float d2  = (sxv - 2.0f * dot) + sume[k];
      if (d2 < bv || (d2 == bv && k < bi)) { bv = d2; bi = k; }
    }
    #pragma unroll
    for (int off = 1; off < 64; off <<= 1) {
      float ov = __shfl_xor(bv, off, 64);
      int   oi = __shfl_xor(bi, off, 64);
      if (ov < bv || (ov == bv && oi < bi)) { bv = ov; bi = oi; }
    }
    int w = tid >> 6;
    if ((tid & 63) == 0) { redv[w] = bv; redi[w] = bi; }
    __syncthreads();
    if (tid == 0) {
      #pragma unroll
      for (int ww = 1; ww < 4; ++ww)
        if (redv[ww] < bv || (redv[ww] == bv && redi[ww] < bi)) { bv = redv[ww]; bi = redi[ww]; }
      idx_ws[token] = bi;
      int b = token >> 11, n = token & (NTOK - 1);
      idxf[(size_t)b * (CBOOKS * NTOK) + n] = (float)bi;
    }
  }
}

// Fused update (r7-verified).
__global__ __launch_bounds__(256) void rvq_zq_resid_kernel(
    const float* __restrict__ xsrc, const float* __restrict__ cbc,
    const int* __restrict__ idx_ws, float* __restrict__ zq,
    float* __restrict__ xdst, int first, int last) {
  #pragma clang fp contract(off)
  int gid   = blockIdx.x * 256 + threadIdx.x;
  int token = gid >> 6;
  int q     = gid & 63;
  int idx   = idx_ws[token];
  float4 e = ((const float4*)cbc)[(size_t)idx * 64 + q];
  float4 x = ((const float4*)xsrc)[gid];
  float4 zi;
  zi.x = x.x + (e.x - x.x); zi.y = x.y + (e.y - x.y);
  zi.z = x.z + (e.z - x.z); zi.w = x.w + (e.w - x.w);
  float4 zo;
  if (first) { zo = zi; }
  else {
    float4 z = ((float4*)zq)[gid];
    zo.x = z.x + zi.x; zo.y = z.y + zi.y; zo.z = z.z + zi.z; zo.w = z.w + zi.w;
  }
  ((float4*)zq)[gid] = zo;
  if (!last) {
    float4 xn;
    xn.x = x.x - zo.x; xn.y = x.y - zo.y; xn.z = x.z - zo.z; xn.w = x.w - zo.w;
    ((float4*)xdst)[gid] = xn;
  }
}

// ---------------------------------------------------------------------------
extern "C" void kernel_launch(void* const* d_in, const int* in_sizes, int n_in,
                              void* d_out, int out_size, void* d_ws, size_t ws_size,
                              hipStream_t stream) {
  const float* x_in = (const float*)d_in[0];
  const float* cbs  = (const float*)d_in[1];
  float* zq      = (float*)d_out;
  float* idxbase = (float*)d_out + ZQ_ELEMS;

  // proven 40 MB footprint (r7/r10/r11/r14)
  char* ws = (char*)d_ws;
  float*  sume     = (float*)ws;                     // 32 KB
  int*    idx_ws   = (int*)(ws + (256 << 10));       // 128 KB
  int*    fix_list = (int*)(ws + (448 << 10));       // 128 KB
  int*    fix_cnt  = (int*)(ws + (640 << 10));       // 4 B
  float4* part     = (float4*)(ws + (1 << 20));      // 4 MB
  float*  xr       = (float*)(ws + (8 << 20));       // 32 MB -> ends 40 MB

  rvq_norms_kernel<<<32, 256, 0, stream>>>(cbs, sume);
  for (int c = 0; c < CBOOKS; ++c) {
    const float* src = (c == 0) ? x_in : xr;
    const float* cbc = cbs + (size_t)c * KCB * DIM;
    float* idxf = idxbase + (size_t)c * NTOK;
    rvq_screen_kernel<<<2048, 256, 0, stream>>>(
        src, cbc, sume + (size_t)c * KCB, part, fix_cnt);
    rvq_merge_kernel<<<128, 256, 0, stream>>>(
        part, idx_ws, fix_list, fix_cnt, idxf);
    rvq_fixup_kernel<<<256, 256, 0, stream>>>(
        src, cbc, sume + (size_t)c * KCB, fix_list, fix_cnt, idx_ws, idxf);
    rvq_zq_resid_kernel<<<8192, 256, 0, stream>>>(
        src, cbc, idx_ws, zq, xr, c == 0, c == CBOOKS - 1);
  }
}

// Round 16
// 1152.306 us; speedup vs baseline: 1.1033x; 1.1033x over previous
//
#include <hip/hip_runtime.h>

#define TOKENS   32768
#define DIM      256
#define KCB      1024
#define CBOOKS   8
#define NTOK     2048
#define ZQ_ELEMS (TOKENS * DIM)
#define EPS_GAP  2.0e-2f

typedef _Float16 f16x8 __attribute__((ext_vector_type(8)));
typedef float    f32x4 __attribute__((ext_vector_type(4)));

// ---------------------------------------------------------------------------
// numpy pairwise sum of squares (verified bit-exact, r6).
// ---------------------------------------------------------------------------
__device__ float np_pairwise_sumsq_256(const float4* a4) {
  #pragma clang fp contract(off)
  float h[2];
  for (int hh = 0; hh < 2; ++hh) {
    const float4* b = a4 + hh * 32;
    float4 v0 = b[0], v1 = b[1];
    float r0 = v0.x * v0.x, r1 = v0.y * v0.y, r2 = v0.z * v0.z, r3 = v0.w * v0.w;
    float r4 = v1.x * v1.x, r5 = v1.y * v1.y, r6 = v1.z * v1.z, r7 = v1.w * v1.w;
    for (int t = 1; t < 16; ++t) {
      float4 w0 = b[2 * t], w1 = b[2 * t + 1];
      r0 = r0 + w0.x * w0.x; r1 = r1 + w0.y * w0.y;
      r2 = r2 + w0.z * w0.z; r3 = r3 + w0.w * w0.w;
      r4 = r4 + w1.x * w1.x; r5 = r5 + w1.y * w1.y;
      r6 = r6 + w1.z * w1.z; r7 = r7 + w1.w * w1.w;
    }
    h[hh] = ((r0 + r1) + (r2 + r3)) + ((r4 + r5) + (r6 + r7));
  }
  return h[0] + h[1];
}

__device__ __forceinline__ float4 f4_muladd(float4 a, float4 b, float4 c) {
  #pragma clang fp contract(off)
  float4 r;
  r.x = a.x * b.x + c.x;
  r.y = a.y * b.y + c.y;
  r.z = a.z * b.z + c.z;
  r.w = a.w * b.w + c.w;
  return r;
}

__global__ __launch_bounds__(256) void rvq_norms_kernel(
    const float* __restrict__ cb, float* __restrict__ sume) {
  int row = blockIdx.x * 256 + threadIdx.x;
  sume[row] = np_pairwise_sumsq_256((const float4*)&cb[(size_t)row * DIM]);
}

// ---------------------------------------------------------------------------
// Prepack ONE codebook into fragment-linear fp16 hi/lo (layout identical to
// the r10-diag-verified ldsB mapping): EfC[(nfrag*16 + kb)*64 + lane],
// kb 0-7 = hi(chunk kb), kb 8-15 = lo(chunk kb-8); lane l holds
// e[nfrag*16 + (l&15)][kb*32 + (l>>4)*8 .. +8].
// ---------------------------------------------------------------------------
__global__ __launch_bounds__(256) void rvq_efsplit_kernel(
    const float* __restrict__ cbc, f16x8* __restrict__ EfC) {
  int gw = blockIdx.x * 4 + (threadIdx.x >> 6);   // nfrag 0..63
  int l  = threadIdx.x & 63;
  int row = gw * 16 + (l & 15);
  #pragma unroll
  for (int kb = 0; kb < 8; ++kb) {
    int d0 = kb * 32 + ((l >> 4) << 3);
    float4 u = *(const float4*)&cbc[(size_t)row * DIM + d0];
    float4 v = *(const float4*)&cbc[(size_t)row * DIM + d0 + 4];
    float ev[8] = {u.x, u.y, u.z, u.w, v.x, v.y, v.z, v.w};
    f16x8 hi, lo;
    #pragma unroll
    for (int i = 0; i < 8; ++i) {
      _Float16 h = (_Float16)ev[i];
      hi[i] = h; lo[i] = (_Float16)(ev[i] - (float)h);
    }
    EfC[((size_t)gw * 16 + kb) * 64 + l]     = hi;
    EfC[((size_t)gw * 16 + kb + 8) * 64 + l] = lo;
  }
}

// ---------------------------------------------------------------------------
// MFMA screen (r11-verified values/orientation/merge). B-operand comes from
// prepacked EfC (global, L2-hot, register-loaded) -> ldsB deleted, B
// conversion deleted from hot loop (was 256x redundant). A single-buffered
// in 16 KB LDS, 2 barriers/chunk; B loads issued before the barriers.
// ---------------------------------------------------------------------------
__global__ __launch_bounds__(256) void rvq_screen_kernel(
    const float* __restrict__ xr, const f16x8* __restrict__ EfC,
    const float* __restrict__ sume, float4* __restrict__ part,
    int* __restrict__ fix_cnt) {
  __shared__ f16x8 ldsA[2][8][64];      // [hi/lo][frag][lane], 16 KB

  const int tid  = threadIdx.x;
  const int lane = tid & 63;
  const int wid  = tid >> 6;
  const int wm   = wid & 1;
  const int wn   = wid >> 1;
  const int mtile = blockIdx.x & 255;
  const int ntile = blockIdx.x >> 8;
  const int m0  = mtile * 128;

  if (blockIdx.x == 0 && tid == 0) *fix_cnt = 0;

  // B fragment base for this wave's 64 ks (nfrag = ntile*8 + wn*4 + ni)
  const f16x8* EfW = EfC + ((size_t)(ntile * 8 + wn * 4) * 16) * 64 + lane;

  f32x4 acc[4][4];
  #pragma unroll
  for (int mi = 0; mi < 4; ++mi)
    #pragma unroll
    for (int ni = 0; ni < 4; ++ni) acc[mi][ni] = (f32x4){0.f, 0.f, 0.f, 0.f};

  float4 ga[2][2];                      // in-flight A staging registers

#define LOADG(KC_)                                                           \
  { _Pragma("unroll")                                                        \
    for (int j = 0; j < 2; ++j) {                                            \
      int item = j * 256 + tid;                                              \
      int row = item >> 2, q8 = item & 3;                                    \
      const float* sa = &xr[(size_t)(m0 + row) * DIM + (KC_) * 32 + q8 * 8]; \
      ga[j][0] = *(const float4*)sa; ga[j][1] = *(const float4*)(sa + 4);    \
    } }

#define CVW()                                                                \
  { _Pragma("unroll")                                                        \
    for (int j = 0; j < 2; ++j) {                                            \
      int item = j * 256 + tid;                                              \
      int row = item >> 2, q8 = item & 3;                                    \
      int fl = (row & 15) + 16 * q8, fr = row >> 4;                          \
      float4 u = ga[j][0], v = ga[j][1];                                     \
      float xv[8] = {u.x, u.y, u.z, u.w, v.x, v.y, v.z, v.w};                \
      f16x8 hi, lo;                                                          \
      _Pragma("unroll")                                                      \
      for (int i = 0; i < 8; ++i) {                                          \
        _Float16 h = (_Float16)xv[i];                                        \
        hi[i] = h; lo[i] = (_Float16)(xv[i] - (float)h);                     \
      }                                                                      \
      ldsA[0][fr][fl] = hi; ldsA[1][fr][fl] = lo;                            \
    } }

  LOADG(0)
  for (int kc = 0; kc < 8; ++kc) {
    // issue B loads for this chunk early (global, no LDS dependency)
    f16x8 bh[4], bl[4];
    #pragma unroll
    for (int ni = 0; ni < 4; ++ni) {
      bh[ni] = EfW[(size_t)ni * 1024 + (size_t)kc * 64];
      bl[ni] = EfW[(size_t)ni * 1024 + (size_t)(kc + 8) * 64];
    }
    if (kc) __syncthreads();            // previous chunk's readers done
    CVW()                               // ga -> fp16 hi/lo -> ldsA
    if (kc < 7) LOADG(kc + 1)           // prefetch next A chunk
    __syncthreads();
    f16x8 ah[4], al[4];
    #pragma unroll
    for (int i = 0; i < 4; ++i) {
      ah[i] = ldsA[0][wm * 4 + i][lane];
      al[i] = ldsA[1][wm * 4 + i][lane];
    }
    #pragma unroll
    for (int mi = 0; mi < 4; ++mi)
      #pragma unroll
      for (int ni = 0; ni < 4; ++ni) {
        acc[mi][ni] = __builtin_amdgcn_mfma_f32_16x16x32_f16(
            ah[mi], bh[ni], acc[mi][ni], 0, 0, 0);
        acc[mi][ni] = __builtin_amdgcn_mfma_f32_16x16x32_f16(
            al[mi], bh[ni], acc[mi][ni], 0, 0, 0);
        acc[mi][ni] = __builtin_amdgcn_mfma_f32_16x16x32_f16(
            ah[mi], bl[ni], acc[mi][ni], 0, 0, 0);
      }
  }
#undef LOADG
#undef CVW
  __syncthreads();                      // all ds_reads done before scr reuse

  // ---- epilogue: per-wave (64-k half) best/second, then cross-wn merge ----
  float* scr = (float*)&ldsA[0][0][0];
  const int n0 = ntile * 128 + wn * 64;
  float se[4];
  #pragma unroll
  for (int ni = 0; ni < 4; ++ni) se[ni] = sume[n0 + ni * 16 + (lane & 15)];

  #pragma unroll
  for (int mi = 0; mi < 4; ++mi) {
    #pragma unroll
    for (int r = 0; r < 4; ++r) {
      float v1 = 3.0e38f, v2 = 3.0e38f; int i1 = 0x7fffffff;
      #pragma unroll
      for (int ni = 0; ni < 4; ++ni) {
        float key = fmaf(-2.0f, acc[mi][ni][r], se[ni]);
        int   k   = n0 + ni * 16 + (lane & 15);
        if (key < v1 || (key == v1 && k < i1)) { v2 = v1; v1 = key; i1 = k; }
        else { v2 = fminf(v2, key); }
      }
      #pragma unroll
      for (int off = 1; off < 16; off <<= 1) {
        float ov1 = __shfl_xor(v1, off, 64);
        int   oi1 = __shfl_xor(i1, off, 64);
        float ov2 = __shfl_xor(v2, off, 64);
        if (ov1 < v1 || (ov1 == v1 && oi1 < i1)) { v2 = fminf(ov2, v1); v1 = ov1; i1 = oi1; }
        else { v2 = fminf(v2, fminf(ov1, ov2)); }
      }
      if ((lane & 15) == 0) {
        int tl = wm * 64 + mi * 16 + (lane >> 4) * 4 + r;   // 0..127
        scr[wn * 384 + tl]       = v1;
        scr[wn * 384 + 128 + tl] = __int_as_float(i1);
        scr[wn * 384 + 256 + tl] = v2;
      }
    }
  }
  __syncthreads();

  if (tid < 128) {
    float av1 = scr[tid],        av2 = scr[256 + tid];
    int   ai  = __float_as_int(scr[128 + tid]);
    float bv1 = scr[384 + tid],  bv2 = scr[384 + 256 + tid];
    int   bi  = __float_as_int(scr[384 + 128 + tid]);
    float v1, v2; int i1;
    if (bv1 < av1) { v1 = bv1; i1 = bi; v2 = fminf(bv2, av1); }   // tie -> a (lower k)
    else           { v1 = av1; i1 = ai; v2 = fminf(av2, bv1); }
    part[(size_t)ntile * TOKENS + m0 + tid] =
        make_float4(v1, __int_as_float(i1), v2, 0.0f);
  }
}

// Merge 8 n-tile partials; near-ties appended to compact fixup list.
__global__ __launch_bounds__(256) void rvq_merge_kernel(
    const float4* __restrict__ part, int* __restrict__ idx_ws,
    int* __restrict__ fix_list, int* __restrict__ fix_cnt,
    float* __restrict__ idxf) {
  int token = blockIdx.x * 256 + threadIdx.x;
  float v1 = 3.0e38f, v2 = 3.0e38f; int i1 = 0x7fffffff;
  #pragma unroll
  for (int j = 0; j < 8; ++j) {
    float4 p = part[(size_t)j * TOKENS + token];
    float ov1 = p.x, ov2 = p.z; int oi1 = __float_as_int(p.y);
    if (ov1 < v1 || (ov1 == v1 && oi1 < i1)) { v2 = fminf(ov2, v1); v1 = ov1; i1 = oi1; }
    else { v2 = fminf(v2, fminf(ov1, ov2)); }
  }
  idx_ws[token] = i1;
  if (v2 - v1 < EPS_GAP) {
    int pos = atomicAdd(fix_cnt, 1);
    fix_list[pos] = token;
  }
  int b = token >> 11, n = token & (NTOK - 1);
  idxf[(size_t)b * (CBOOKS * NTOK) + n] = (float)i1;
}

// Exact numpy rescan over the compacted flagged-token list (r14-verified:
// register-budgeted, unroll-1, no spill).
__global__ __launch_bounds__(256, 2) void rvq_fixup_kernel(
    const float* __restrict__ xr, const float* __restrict__ cbc,
    const float* __restrict__ sume, const int* __restrict__ fix_list,
    const int* __restrict__ fix_cnt, int* __restrict__ idx_ws,
    float* __restrict__ idxf) {
  #pragma clang fp contract(off)
  __shared__ float xs[DIM];
  __shared__ float redv[4];
  __shared__ int   redi[4];
  __shared__ float sxv_sh;
  const int tid  = threadIdx.x;
  const int nfix = *fix_cnt;

  #pragma unroll 1
  for (int i = blockIdx.x; i < nfix; i += gridDim.x) {
    int token = fix_list[i];
    __syncthreads();                           // xs reuse guard
    if (tid < 64)
      ((float4*)xs)[tid] = ((const float4*)xr)[(size_t)token * 64 + tid];
    __syncthreads();
    // inline np-exact sumx: lanes 0-15 run the 16 stride-8 chains, then
    // a 4-step butterfly reproduces the exact pairwise combine tree.
    if (tid < 64) {
      float s = 0.f;
      if ((tid & 63) < 16) {
        int j = tid & 7, hh = (tid >> 3) & 1;
        const float* bb = xs + hh * 128;
        float r = bb[j] * bb[j];
        #pragma unroll 1
        for (int t = 1; t < 16; ++t) r = r + bb[8 * t + j] * bb[8 * t + j];
        s = r;
      }
      #pragma unroll
      for (int off = 1; off <= 8; off <<= 1)
        s = s + __shfl_xor(s, off, 64);        // commutative pairs -> exact tree
      if (tid == 0) sxv_sh = s;
    }
    __syncthreads();
    float sxv = sxv_sh;
    float bv = 3.0e38f; int bi = 0x7fffffff;
    #pragma unroll 1
    for (int kk = 0; kk < 4; ++kk) {
      int k = kk * 256 + tid;
      float4 vacc = {0.f, 0.f, 0.f, 0.f};
      #pragma unroll 1
      for (int t = 0; t < 16; ++t) {
        float4 ab = vacc;
        #pragma unroll
        for (int j = 3; j >= 0; --j) {         // reverse-chained npyv block
          float4 xq = *(const float4*)&xs[t * 16 + j * 4];
          float4 eq = *(const float4*)&cbc[(size_t)k * DIM + t * 16 + j * 4];
          ab = f4_muladd(xq, eq, ab);
        }
        vacc = ab;
      }
      float dot = (vacc.x + vacc.y) + (vacc.z + vacc.w);
      float d2  = (sxv - 2.0f * dot) + sume[k];
      if (d2 < bv || (d2 == bv && k < bi)) { bv = d2; bi = k; }
    }
    #pragma unroll
    for (int off = 1; off < 64; off <<= 1) {
      float ov = __shfl_xor(bv, off, 64);
      int   oi = __shfl_xor(bi, off, 64);
      if (ov < bv || (ov == bv && oi < bi)) { bv = ov; bi = oi; }
    }
    int w = tid >> 6;
    if ((tid & 63) == 0) { redv[w] = bv; redi[w] = bi; }
    __syncthreads();
    if (tid == 0) {
      #pragma unroll
      for (int ww = 1; ww < 4; ++ww)
        if (redv[ww] < bv || (redv[ww] == bv && redi[ww] < bi)) { bv = redv[ww]; bi = redi[ww]; }
      idx_ws[token] = bi;
      int b = token >> 11, n = token & (NTOK - 1);
      idxf[(size_t)b * (CBOOKS * NTOK) + n] = (float)bi;
    }
  }
}

// Fused update (r7-verified).
__global__ __launch_bounds__(256) void rvq_zq_resid_kernel(
    const float* __restrict__ xsrc, const float* __restrict__ cbc,
    const int* __restrict__ idx_ws, float* __restrict__ zq,
    float* __restrict__ xdst, int first, int last) {
  #pragma clang fp contract(off)
  int gid   = blockIdx.x * 256 + threadIdx.x;
  int token = gid >> 6;
  int q     = gid & 63;
  int idx   = idx_ws[token];
  float4 e = ((const float4*)cbc)[(size_t)idx * 64 + q];
  float4 x = ((const float4*)xsrc)[gid];
  float4 zi;
  zi.x = x.x + (e.x - x.x); zi.y = x.y + (e.y - x.y);
  zi.z = x.z + (e.z - x.z); zi.w = x.w + (e.w - x.w);
  float4 zo;
  if (first) { zo = zi; }
  else {
    float4 z = ((float4*)zq)[gid];
    zo.x = z.x + zi.x; zo.y = z.y + zi.y; zo.z = z.z + zi.z; zo.w = z.w + zi.w;
  }
  ((float4*)zq)[gid] = zo;
  if (!last) {
    float4 xn;
    xn.x = x.x - zo.x; xn.y = x.y - zo.y; xn.z = x.z - zo.z; xn.w = x.w - zo.w;
    ((float4*)xdst)[gid] = xn;
  }
}

// ---------------------------------------------------------------------------
extern "C" void kernel_launch(void* const* d_in, const int* in_sizes, int n_in,
                              void* d_out, int out_size, void* d_ws, size_t ws_size,
                              hipStream_t stream) {
  const float* x_in = (const float*)d_in[0];
  const float* cbs  = (const float*)d_in[1];
  float* zq      = (float*)d_out;
  float* idxbase = (float*)d_out + ZQ_ELEMS;

  // proven 40 MB footprint (r7/r10/r11/r14); Ef fills the free 5-6 MB gap
  char* ws = (char*)d_ws;
  float*  sume     = (float*)ws;                     // 32 KB
  int*    idx_ws   = (int*)(ws + (256 << 10));       // 128 KB
  int*    fix_list = (int*)(ws + (448 << 10));       // 128 KB
  int*    fix_cnt  = (int*)(ws + (640 << 10));       // 4 B
  float4* part     = (float4*)(ws + (1 << 20));      // 4 MB  -> ends 5 MB
  f16x8*  EfC      = (f16x8*)(ws + (5 << 20));       // 1 MB  -> ends 6 MB
  float*  xr       = (float*)(ws + (8 << 20));       // 32 MB -> ends 40 MB

  rvq_norms_kernel<<<32, 256, 0, stream>>>(cbs, sume);
  for (int c = 0; c < CBOOKS; ++c) {
    const float* src = (c == 0) ? x_in : xr;
    const float* cbc = cbs + (size_t)c * KCB * DIM;
    float* idxf = idxbase + (size_t)c * NTOK;
    rvq_efsplit_kernel<<<16, 256, 0, stream>>>(cbc, EfC);
    rvq_screen_kernel<<<2048, 256, 0, stream>>>(
        src, EfC, sume + (size_t)c * KCB, part, fix_cnt);
    rvq_merge_kernel<<<128, 256, 0, stream>>>(
        part, idx_ws, fix_list, fix_cnt, idxf);
    rvq_fixup_kernel<<<256, 256, 0, stream>>>(
        src, cbc, sume + (size_t)c * KCB, fix_list, fix_cnt, idx_ws, idxf);
    rvq_zq_resid_kernel<<<8192, 256, 0, stream>>>(
        src, cbc, idx_ws, zq, xr, c == 0, c == CBOOKS - 1);
  }
}

// Round 17
// 1113.867 us; speedup vs baseline: 1.1414x; 1.0345x over previous
//
#include <hip/hip_runtime.h>

#define TOKENS   32768
#define DIM      256
#define KCB      1024
#define CBOOKS   8
#define NTOK     2048
#define ZQ_ELEMS (TOKENS * DIM)
#define EPS_GAP  2.0e-2f

typedef _Float16 f16x8 __attribute__((ext_vector_type(8)));
typedef float    f32x4 __attribute__((ext_vector_type(4)));

// ---------------------------------------------------------------------------
// numpy pairwise sum of squares (verified bit-exact, r6).
// ---------------------------------------------------------------------------
__device__ float np_pairwise_sumsq_256(const float4* a4) {
  #pragma clang fp contract(off)
  float h[2];
  for (int hh = 0; hh < 2; ++hh) {
    const float4* b = a4 + hh * 32;
    float4 v0 = b[0], v1 = b[1];
    float r0 = v0.x * v0.x, r1 = v0.y * v0.y, r2 = v0.z * v0.z, r3 = v0.w * v0.w;
    float r4 = v1.x * v1.x, r5 = v1.y * v1.y, r6 = v1.z * v1.z, r7 = v1.w * v1.w;
    for (int t = 1; t < 16; ++t) {
      float4 w0 = b[2 * t], w1 = b[2 * t + 1];
      r0 = r0 + w0.x * w0.x; r1 = r1 + w0.y * w0.y;
      r2 = r2 + w0.z * w0.z; r3 = r3 + w0.w * w0.w;
      r4 = r4 + w1.x * w1.x; r5 = r5 + w1.y * w1.y;
      r6 = r6 + w1.z * w1.z; r7 = r7 + w1.w * w1.w;
    }
    h[hh] = ((r0 + r1) + (r2 + r3)) + ((r4 + r5) + (r6 + r7));
  }
  return h[0] + h[1];
}

__device__ __forceinline__ float4 f4_muladd(float4 a, float4 b, float4 c) {
  #pragma clang fp contract(off)
  float4 r;
  r.x = a.x * b.x + c.x;
  r.y = a.y * b.y + c.y;
  r.z = a.z * b.z + c.z;
  r.w = a.w * b.w + c.w;
  return r;
}

__global__ __launch_bounds__(256) void rvq_norms_kernel(
    const float* __restrict__ cb, float* __restrict__ sume) {
  int row = blockIdx.x * 256 + threadIdx.x;
  sume[row] = np_pairwise_sumsq_256((const float4*)&cb[(size_t)row * DIM]);
}

// ---------------------------------------------------------------------------
// Prepack ONE codebook into fragment-linear fp16 hi/lo (r16-verified layout).
// Also zeroes the fixup counter (separate dispatch -> no race with screen).
// ---------------------------------------------------------------------------
__global__ __launch_bounds__(256) void rvq_efsplit_kernel(
    const float* __restrict__ cbc, f16x8* __restrict__ EfC,
    int* __restrict__ fix_cnt) {
  if (blockIdx.x == 0 && threadIdx.x == 0) *fix_cnt = 0;
  int gw = blockIdx.x * 4 + (threadIdx.x >> 6);   // nfrag 0..63
  int l  = threadIdx.x & 63;
  int row = gw * 16 + (l & 15);
  #pragma unroll
  for (int kb = 0; kb < 8; ++kb) {
    int d0 = kb * 32 + ((l >> 4) << 3);
    float4 u = *(const float4*)&cbc[(size_t)row * DIM + d0];
    float4 v = *(const float4*)&cbc[(size_t)row * DIM + d0 + 4];
    float ev[8] = {u.x, u.y, u.z, u.w, v.x, v.y, v.z, v.w};
    f16x8 hi, lo;
    #pragma unroll
    for (int i = 0; i < 8; ++i) {
      _Float16 h = (_Float16)ev[i];
      hi[i] = h; lo[i] = (_Float16)(ev[i] - (float)h);
    }
    EfC[((size_t)gw * 16 + kb) * 64 + l]     = hi;
    EfC[((size_t)gw * 16 + kb + 8) * 64 + l] = lo;
  }
}

// ---------------------------------------------------------------------------
// MFMA screen v3: 512 blocks x 256 thr (4 waves), block owns 64 tokens.
// A: this wave's 16 tokens, full K, in REGISTERS (converted once per token).
// B: prepacked EfC staged per (ntile,kc) into 32KB double-buffered LDS,
//    shared by all 4 waves. ntile loops inside the block; best/second merged
//    in-register across ntiles (r16 merge semantics; values bit-identical).
// Writes idx_ws / near-tie list / idxf directly (merge kernel deleted).
// ---------------------------------------------------------------------------
__global__ __launch_bounds__(256, 2) void rvq_screen_kernel(
    const float* __restrict__ xr, const f16x8* __restrict__ EfC,
    const float* __restrict__ sume, int* __restrict__ idx_ws,
    int* __restrict__ fix_list, int* __restrict__ fix_cnt,
    float* __restrict__ idxf) {
  __shared__ f16x8 ldsB[2][8][2][64];   // [buf][ni][hi/lo][lane], 32 KB

  const int tid  = threadIdx.x;
  const int lane = tid & 63;
  const int w    = tid >> 6;            // wave 0..3
  const int m0w  = blockIdx.x * 64 + w * 16;

  // ---- A: load + convert this wave's 16 tokens (full K) into registers ----
  f16x8 ah[8], al[8];
  {
    const float* base = &xr[(size_t)(m0w + (lane & 15)) * DIM + ((lane >> 4) << 3)];
    #pragma unroll
    for (int kc = 0; kc < 8; ++kc) {
      float4 u = *(const float4*)(base + kc * 32);
      float4 v = *(const float4*)(base + kc * 32 + 4);
      float xv[8] = {u.x, u.y, u.z, u.w, v.x, v.y, v.z, v.w};
      #pragma unroll
      for (int i = 0; i < 8; ++i) {
        _Float16 h = (_Float16)xv[i];
        ah[kc][i] = h; al[kc][i] = (_Float16)(xv[i] - (float)h);
      }
    }
  }

  float rv1[4], rv2[4]; int ri1[4];
  #pragma unroll
  for (int r = 0; r < 4; ++r) { rv1[r] = 3.0e38f; rv2[r] = 3.0e38f; ri1[r] = 0x7fffffff; }

  // B stage: 16KB per (ntile,kc): 1024 f16x8 entries, 4 per thread.
#define STAGE_B(BUF, NT, KC)                                                 \
  { _Pragma("unroll")                                                        \
    for (int cc = 0; cc < 4; ++cc) {                                         \
      int e = cc * 256 + tid;                                                \
      int ln = e & 63, p = e >> 6;          /* piece 0..15 */                \
      int ni = p >> 1, half = p & 1;                                         \
      ldsB[BUF][ni][half][ln] =                                              \
          EfC[(((size_t)(NT) * 8 + ni) * 16 + (half ? (KC) + 8 : (KC))) * 64 + ln]; \
    } }

  f32x4 acc[8];
  #pragma unroll
  for (int ni = 0; ni < 8; ++ni) acc[ni] = (f32x4){0.f, 0.f, 0.f, 0.f};

  STAGE_B(0, 0, 0)
  __syncthreads();

  #pragma unroll 1
  for (int ntile = 0; ntile < 8; ++ntile) {
    #pragma unroll
    for (int kc = 0; kc < 8; ++kc) {                // static kc -> ah[kc] in regs
      const int buf = kc & 1;                       // buf parity: ntile*8+kc even/odd
      if (ntile * 8 + kc < 63) {
        int nt2 = (kc < 7) ? ntile : ntile + 1;
        STAGE_B(buf ^ 1, nt2, (kc + 1) & 7)
      }
      #pragma unroll
      for (int ni = 0; ni < 8; ++ni) {
        f16x8 bh = ldsB[buf][ni][0][lane];
        f16x8 bl = ldsB[buf][ni][1][lane];
        acc[ni] = __builtin_amdgcn_mfma_f32_16x16x32_f16(ah[kc], bh, acc[ni], 0, 0, 0);
        acc[ni] = __builtin_amdgcn_mfma_f32_16x16x32_f16(al[kc], bh, acc[ni], 0, 0, 0);
        acc[ni] = __builtin_amdgcn_mfma_f32_16x16x32_f16(ah[kc], bl, acc[ni], 0, 0, 0);
      }
      __syncthreads();
    }
    // ---- epilogue for this ntile: best/second over 128 ks, merge running ----
    const int n0 = ntile * 128;
    float se[8];
    #pragma unroll
    for (int ni = 0; ni < 8; ++ni) se[ni] = sume[n0 + ni * 16 + (lane & 15)];
    #pragma unroll
    for (int r = 0; r < 4; ++r) {
      float v1 = 3.0e38f, v2 = 3.0e38f; int i1 = 0x7fffffff;
      #pragma unroll
      for (int ni = 0; ni < 8; ++ni) {
        float key = fmaf(-2.0f, acc[ni][r], se[ni]);
        int   k   = n0 + ni * 16 + (lane & 15);
        if (key < v1 || (key == v1 && k < i1)) { v2 = v1; v1 = key; i1 = k; }
        else { v2 = fminf(v2, key); }
      }
      #pragma unroll
      for (int off = 1; off < 16; off <<= 1) {
        float ov1 = __shfl_xor(v1, off, 64);
        int   oi1 = __shfl_xor(i1, off, 64);
        float ov2 = __shfl_xor(v2, off, 64);
        if (ov1 < v1 || (ov1 == v1 && oi1 < i1)) { v2 = fminf(ov2, v1); v1 = ov1; i1 = oi1; }
        else { v2 = fminf(v2, fminf(ov1, ov2)); }
      }
      if (v1 < rv1[r] || (v1 == rv1[r] && i1 < ri1[r])) {
        rv2[r] = fminf(rv1[r], v2); rv1[r] = v1; ri1[r] = i1;
      } else { rv2[r] = fminf(rv2[r], fminf(v1, v2)); }
    }
    #pragma unroll
    for (int ni = 0; ni < 8; ++ni) acc[ni] = (f32x4){0.f, 0.f, 0.f, 0.f};
  }
#undef STAGE_B

  if ((lane & 15) == 0) {
    #pragma unroll
    for (int r = 0; r < 4; ++r) {
      int token = m0w + (lane >> 4) * 4 + r;
      idx_ws[token] = ri1[r];
      if (rv2[r] - rv1[r] < EPS_GAP) {
        int pos = atomicAdd(fix_cnt, 1);
        fix_list[pos] = token;
      }
      int b = token >> 11, n = token & (NTOK - 1);
      idxf[(size_t)b * (CBOOKS * NTOK) + n] = (float)ri1[r];
    }
  }
}

// Exact numpy rescan over the compacted flagged-token list (r14-verified:
// register-budgeted, unroll-1, no spill).
__global__ __launch_bounds__(256, 2) void rvq_fixup_kernel(
    const float* __restrict__ xr, const float* __restrict__ cbc,
    const float* __restrict__ sume, const int* __restrict__ fix_list,
    const int* __restrict__ fix_cnt, int* __restrict__ idx_ws,
    float* __restrict__ idxf) {
  #pragma clang fp contract(off)
  __shared__ float xs[DIM];
  __shared__ float redv[4];
  __shared__ int   redi[4];
  __shared__ float sxv_sh;
  const int tid  = threadIdx.x;
  const int nfix = *fix_cnt;

  #pragma unroll 1
  for (int i = blockIdx.x; i < nfix; i += gridDim.x) {
    int token = fix_list[i];
    __syncthreads();                           // xs reuse guard
    if (tid < 64)
      ((float4*)xs)[tid] = ((const float4*)xr)[(size_t)token * 64 + tid];
    __syncthreads();
    if (tid < 64) {
      float s = 0.f;
      if ((tid & 63) < 16) {
        int j = tid & 7, hh = (tid >> 3) & 1;
        const float* bb = xs + hh * 128;
        float r = bb[j] * bb[j];
        #pragma unroll 1
        for (int t = 1; t < 16; ++t) r = r + bb[8 * t + j] * bb[8 * t + j];
        s = r;
      }
      #pragma unroll
      for (int off = 1; off <= 8; off <<= 1)
        s = s + __shfl_xor(s, off, 64);        // commutative pairs -> exact tree
      if (tid == 0) sxv_sh = s;
    }
    __syncthreads();
    float sxv = sxv_sh;
    float bv = 3.0e38f; int bi = 0x7fffffff;
    #pragma unroll 1
    for (int kk = 0; kk < 4; ++kk) {
      int k = kk * 256 + tid;
      float4 vacc = {0.f, 0.f, 0.f, 0.f};
      #pragma unroll 1
      for (int t = 0; t < 16; ++t) {
        float4 ab = vacc;
        #pragma unroll
        for (int j = 3; j >= 0; --j) {         // reverse-chained npyv block
          float4 xq = *(const float4*)&xs[t * 16 + j * 4];
          float4 eq = *(const float4*)&cbc[(size_t)k * DIM + t * 16 + j * 4];
          ab = f4_muladd(xq, eq, ab);
        }
        vacc = ab;
      }
      float dot = (vacc.x + vacc.y) + (vacc.z + vacc.w);
      float d2  = (sxv - 2.0f * dot) + sume[k];
      if (d2 < bv || (d2 == bv && k < bi)) { bv = d2; bi = k; }
    }
    #pragma unroll
    for (int off = 1; off < 64; off <<= 1) {
      float ov = __shfl_xor(bv, off, 64);
      int   oi = __shfl_xor(bi, off, 64);
      if (ov < bv || (ov == bv && oi < bi)) { bv = ov; bi = oi; }
    }
    int w = tid >> 6;
    if ((tid & 63) == 0) { redv[w] = bv; redi[w] = bi; }
    __syncthreads();
    if (tid == 0) {
      #pragma unroll
      for (int ww = 1; ww < 4; ++ww)
        if (redv[ww] < bv || (redv[ww] == bv && redi[ww] < bi)) { bv = redv[ww]; bi = redi[ww]; }
      idx_ws[token] = bi;
      int b = token >> 11, n = token & (NTOK - 1);
      idxf[(size_t)b * (CBOOKS * NTOK) + n] = (float)bi;
    }
  }
}

// Fused update (r7-verified).
__global__ __launch_bounds__(256) void rvq_zq_resid_kernel(
    const float* __restrict__ xsrc, const float* __restrict__ cbc,
    const int* __restrict__ idx_ws, float* __restrict__ zq,
    float* __restrict__ xdst, int first, int last) {
  #pragma clang fp contract(off)
  int gid   = blockIdx.x * 256 + threadIdx.x;
  int token = gid >> 6;
  int q     = gid & 63;
  int idx   = idx_ws[token];
  float4 e = ((const float4*)cbc)[(size_t)idx * 64 + q];
  float4 x = ((const float4*)xsrc)[gid];
  float4 zi;
  zi.x = x.x + (e.x - x.x); zi.y = x.y + (e.y - x.y);
  zi.z = x.z + (e.z - x.z); zi.w = x.w + (e.w - x.w);
  float4 zo;
  if (first) { zo = zi; }
  else {
    float4 z = ((float4*)zq)[gid];
    zo.x = z.x + zi.x; zo.y = z.y + zi.y; zo.z = z.z + zi.z; zo.w = z.w + zi.w;
  }
  ((float4*)zq)[gid] = zo;
  if (!last) {
    float4 xn;
    xn.x = x.x - zo.x; xn.y = x.y - zo.y; xn.z = x.z - zo.z; xn.w = x.w - zo.w;
    ((float4*)xdst)[gid] = xn;
  }
}

// ---------------------------------------------------------------------------
extern "C" void kernel_launch(void* const* d_in, const int* in_sizes, int n_in,
                              void* d_out, int out_size, void* d_ws, size_t ws_size,
                              hipStream_t stream) {
  const float* x_in = (const float*)d_in[0];
  const float* cbs  = (const float*)d_in[1];
  float* zq      = (float*)d_out;
  float* idxbase = (float*)d_out + ZQ_ELEMS;

  // proven 40 MB footprint (r7..r16); part buffer no longer needed
  char* ws = (char*)d_ws;
  float*  sume     = (float*)ws;                     // 32 KB
  int*    idx_ws   = (int*)(ws + (256 << 10));       // 128 KB
  int*    fix_list = (int*)(ws + (448 << 10));       // 128 KB
  int*    fix_cnt  = (int*)(ws + (640 << 10));       // 4 B
  f16x8*  EfC      = (f16x8*)(ws + (5 << 20));       // 1 MB
  float*  xr       = (float*)(ws + (8 << 20));       // 32 MB -> ends 40 MB

  rvq_norms_kernel<<<32, 256, 0, stream>>>(cbs, sume);
  for (int c = 0; c < CBOOKS; ++c) {
    const float* src = (c == 0) ? x_in : xr;
    const float* cbc = cbs + (size_t)c * KCB * DIM;
    float* idxf = idxbase + (size_t)c * NTOK;
    rvq_efsplit_kernel<<<16, 256, 0, stream>>>(cbc, EfC, fix_cnt);
    rvq_screen_kernel<<<512, 256, 0, stream>>>(
        src, EfC, sume + (size_t)c * KCB, idx_ws, fix_list, fix_cnt, idxf);
    rvq_fixup_kernel<<<256, 256, 0, stream>>>(
        src, cbc, sume + (size_t)c * KCB, fix_list, fix_cnt, idx_ws, idxf);
    rvq_zq_resid_kernel<<<8192, 256, 0, stream>>>(
        src, cbc, idx_ws, zq, xr, c == 0, c == CBOOKS - 1);
  }
}